// Round 7
// baseline (132.088 us; speedup 1.0000x reference)
//
#include <hip/hip_runtime.h>

typedef __fp16 f16x2 __attribute__((ext_vector_type(2)));

#define Dm 128
#define Bn 16
#define TZ 4             // tile depth
#define TYt 8            // tile height
#define TXv 16           // tile width in voxels (8 pairs/thread-row)
#define HY 10            // halo height rows
#define WPR 12           // packed f16x2 words per LDS row (24 halves; 18 used)
#define TILE_W 768       // 64 rows x 12 words (60 rows used)
#define NT 256
#define NPAIR 3          // staged words per thread (768/256)
#define VOX (Dm * Dm * Dm)
#define BCH 2
#define NCH (Bn / BCH)

__device__ __forceinline__ int iclamp(int v, int lo, int hi) {
  return v < lo ? lo : (v > hi ? hi : v);
}
__device__ __forceinline__ f16x2 pkrtz(float lo, float hi) {
  return __builtin_amdgcn_cvt_pkrtz(lo, hi);
}
__device__ __forceinline__ float pkbits(float lo, float hi) {
  return __builtin_bit_cast(float, __builtin_amdgcn_cvt_pkrtz(lo, hi));
}
__device__ __forceinline__ f16x2 asf16x2(float w) {
  return __builtin_bit_cast(f16x2, w);
}
// (h01.hi, h23.lo) = middle overlapping pair
__device__ __forceinline__ f16x2 midpair(f16x2 h23, f16x2 h01) {
  unsigned r = __builtin_amdgcn_perm(__builtin_bit_cast(unsigned, h23),
                                     __builtin_bit_cast(unsigned, h01),
                                     0x05040302u);
  return __builtin_bit_cast(f16x2, r);
}

// Pack W (27x27) and bias (27) as duplicated-half f16x2 into workspace.
extern "C" __global__ void packW(const float* __restrict__ Wf,
                                 const float* __restrict__ bfp,
                                 float* __restrict__ wpk) {
  int i = threadIdx.x;
  if (i < 729)       wpk[i] = pkbits(Wf[i], Wf[i]);
  else if (i < 756)  { float b = bfp[i - 729]; wpk[i] = pkbits(b, b); }
}

extern "C" __global__ void __launch_bounds__(NT, 4)
fused3d(const float* __restrict__ img, const float* __restrict__ x,
        const float* __restrict__ wpk, float* __restrict__ out)
{
  __shared__ float sImgP[TILE_W];           // 3 KiB packed f16x2
  __shared__ float sXP[2][BCH][TILE_W];     // 12 KiB double-buffered

  const int tid = threadIdx.x;
  const int tx = tid & 7;          // w-pair 0..7
  const int ty = (tid >> 3) & 7;   // h 0..7
  const int tz = tid >> 6;         // d 0..3 (wave id)

  // T1 XCD swizzle: contiguous slab of 512 spatial tiles per XCD
  const int bid = blockIdx.x;
  const int s  = (bid & 7) * 512 + (bid >> 3);
  const int bx = s & 7, by = (s >> 3) & 15, bz = s >> 7;
  const int w0 = bx * TXv, h0 = by * TYt, d0 = bz * TZ;

  // ---- staging map: LDS word p = k*NT+tid holds x-halves (2p, 2p+1), clamped
  int off0[NPAIR], off1[NPAIR];
  float oki0[NPAIR], oki1[NPAIR];   // img zero-pad masks (conv SAME)
#pragma unroll
  for (int k = 0; k < NPAIR; ++k) {
    int p  = k * NT + tid;          // 0..767
    int r  = p / WPR;               // 0..63 (rows >=60 pad, never read)
    int c  = 2 * (p - r * WPR);     // 0..22 (halves >=18 pad, never read)
    int zz = r / HY;
    int yy = r - zz * HY;
    int gd = d0 + zz - 1, gh = h0 + yy - 1;
    int g0 = w0 + c - 1,  g1 = w0 + c;
    int base = (iclamp(gd, 0, Dm - 1) * Dm + iclamp(gh, 0, Dm - 1)) * Dm;
    off0[k] = base + iclamp(g0, 0, Dm - 1);
    off1[k] = base + iclamp(g1, 0, Dm - 1);
    bool rk = ((unsigned)gd < Dm) & ((unsigned)gh < Dm);
    oki0[k] = (rk & ((unsigned)g0 < Dm)) ? 1.f : 0.f;
    oki1[k] = (rk & ((unsigned)g1 < Dm)) ? 1.f : 0.f;
  }

  // ---- prologue: img (zero-masked) + x chunk 0 -> LDS buf0; ONE barrier
  {
    float ri0[NPAIR], ri1[NPAIR], rx0[BCH][NPAIR], rx1[BCH][NPAIR];
#pragma unroll
    for (int k = 0; k < NPAIR; ++k) {
      ri0[k] = img[off0[k]] * oki0[k];
      ri1[k] = img[off1[k]] * oki1[k];
    }
#pragma unroll
    for (int j = 0; j < BCH; ++j)
#pragma unroll
      for (int k = 0; k < NPAIR; ++k) {
        rx0[j][k] = x[(size_t)j * VOX + off0[k]];
        rx1[j][k] = x[(size_t)j * VOX + off1[k]];
      }
#pragma unroll
    for (int k = 0; k < NPAIR; ++k)
      sImgP[k * NT + tid] = pkbits(ri0[k], ri1[k]);
#pragma unroll
    for (int j = 0; j < BCH; ++j)
#pragma unroll
      for (int k = 0; k < NPAIR; ++k)
        sXP[0][j][k * NT + tid] = pkbits(rx0[j][k], rx1[j][k]);
  }
  __syncthreads();

  // ---- issue chunk 1 loads now: K-gen (~800 instr) covers their latency
  float nx0[BCH][NPAIR], nx1[BCH][NPAIR];
#pragma unroll
  for (int j = 0; j < BCH; ++j)
#pragma unroll
    for (int k = 0; k < NPAIR; ++k) {
      nx0[j][k] = x[(size_t)(BCH + j) * VOX + off0[k]];
      nx1[j][k] = x[(size_t)(BCH + j) * VOX + off1[k]];
    }

  // ---- K-gen: single pass over image window, packed fp16 (W via s_loads)
  const int tbase = (tz * HY + ty) * WPR + tx;
  f16x2 K2[27];
#pragma unroll
  for (int o = 0; o < 27; ++o) K2[o] = asf16x2(wpk[729 + o]);
#pragma unroll
  for (int rr = 0; rr < 9; ++rr) {
    const int wofs = tbase + ((rr / 3) * HY + (rr % 3)) * WPR;
    float u0 = sImgP[wofs], u1 = sImgP[wofs + 1];
    f16x2 h01 = asf16x2(u0), h23 = asf16x2(u1), h12 = midpair(h23, h01);
#pragma unroll
    for (int o = 0; o < 27; ++o) {
      K2[o] = __builtin_elementwise_fma(asf16x2(wpk[o * 27 + rr * 3 + 0]), h01, K2[o]);
      K2[o] = __builtin_elementwise_fma(asf16x2(wpk[o * 27 + rr * 3 + 1]), h12, K2[o]);
      K2[o] = __builtin_elementwise_fma(asf16x2(wpk[o * 27 + rr * 3 + 2]), h23, K2[o]);
    }
  }

  // ---- boundary tap masks (x zero-pad semantics; covers bias too)
  const int od = d0 + tz, oh = h0 + ty, ow = w0 + 2 * tx;
#pragma unroll
  for (int o = 0; o < 27; ++o) {
    const int di = o / 9, dj = (o / 3) % 3, dk = o % 3;
    const bool mm = ((unsigned)(od + di - 1) < Dm) & ((unsigned)(oh + dj - 1) < Dm);
    const float m0 = (mm & ((unsigned)(ow + dk - 1) < Dm)) ? 1.f : 0.f;
    const float m1 = (mm & ((unsigned)(ow + dk)     < Dm)) ? 1.f : 0.f;
    K2[o] *= pkrtz(m0, m1);
  }

  const size_t obase = (((size_t)od) * Dm + oh) * Dm + ow;

  // ---- main loop: dbuf, ONE barrier per chunk.
  // Interval layout: [loads ch+2 issued last iter] compute(buf cur) ->
  // write nx -> barrier -> issue loads ch+2. Load->consume stays inside
  // one barrier interval (syncthreads drains vmcnt(0), m97).
  for (int ch = 0; ch < NCH; ++ch) {
    const int cur = ch & 1;

#pragma unroll
    for (int j = 0; j < BCH; ++j) {
      const float* sx = sXP[cur][j];
      f16x2 aA = {(__fp16)0.f, (__fp16)0.f};
      f16x2 aB = {(__fp16)0.f, (__fp16)0.f};
#pragma unroll
      for (int rr = 0; rr < 9; ++rr) {
        const int wofs = tbase + ((rr / 3) * HY + (rr % 3)) * WPR;
        float u0 = sx[wofs], u1 = sx[wofs + 1];
        f16x2 h01 = asf16x2(u0), h23 = asf16x2(u1), h12 = midpair(h23, h01);
        if (rr & 1) {
          aB = __builtin_elementwise_fma(K2[rr * 3 + 0], h01, aB);
          aB = __builtin_elementwise_fma(K2[rr * 3 + 1], h12, aB);
          aB = __builtin_elementwise_fma(K2[rr * 3 + 2], h23, aB);
        } else {
          aA = __builtin_elementwise_fma(K2[rr * 3 + 0], h01, aA);
          aA = __builtin_elementwise_fma(K2[rr * 3 + 1], h12, aA);
          aA = __builtin_elementwise_fma(K2[rr * 3 + 2], h23, aA);
        }
      }
      f16x2 acc = aA + aB;
      float2 st; st.x = (float)acc.x; st.y = (float)acc.y;
      *(float2*)&out[(size_t)(ch * BCH + j) * VOX + obase] = st;
    }

    if (ch + 1 < NCH) {              // write prefetched chunk into other buffer
#pragma unroll
      for (int j = 0; j < BCH; ++j)
#pragma unroll
        for (int k = 0; k < NPAIR; ++k)
          sXP[cur ^ 1][j][k * NT + tid] = pkbits(nx0[j][k], nx1[j][k]);
    }

    __syncthreads();                 // single barrier per chunk

    if (ch + 2 < NCH) {              // issue loads for chunk+2; next compute covers
      const float* xc = x + (size_t)(ch + 2) * BCH * VOX;
#pragma unroll
      for (int j = 0; j < BCH; ++j)
#pragma unroll
        for (int k = 0; k < NPAIR; ++k) {
          nx0[j][k] = xc[(size_t)j * VOX + off0[k]];
          nx1[j][k] = xc[(size_t)j * VOX + off1[k]];
        }
    }
  }
}

extern "C" void kernel_launch(void* const* d_in, const int* in_sizes, int n_in,
                              void* d_out, int out_size, void* d_ws, size_t ws_size,
                              hipStream_t stream) {
  const float* img = (const float*)d_in[0];
  const float* x   = (const float*)d_in[1];
  const float* Wf  = (const float*)d_in[2];
  const float* bf  = (const float*)d_in[3];
  float* out = (float*)d_out;
  float* wpk = (float*)d_ws;   // 756 floats (3 KiB) of packed f16x2
  hipLaunchKernelGGL(packW, dim3(1), dim3(768), 0, stream, Wf, bf, wpk);
  hipLaunchKernelGGL(fused3d, dim3(4096), dim3(256), 0, stream, img, x, wpk, out);
}

// Round 8
// 128.843 us; speedup vs baseline: 1.0252x; 1.0252x over previous
//
#include <hip/hip_runtime.h>

typedef __fp16 f16x2 __attribute__((ext_vector_type(2)));

#define Dm 128
#define Bn 16
#define TZ 4             // tile depth
#define TYt 8            // tile height
#define TXv 16           // tile width in voxels (8 pairs/thread-row)
#define HY 10            // halo height rows
#define WPR 12           // packed f16x2 words per LDS row (24 halves; 18 used)
#define TILE_W 768       // 64 rows x 12 words (60 rows used)
#define NT 256
#define NPAIR 3          // staged words per thread (768/256)
#define VOX (Dm * Dm * Dm)
#define BCH 4            // batches per chunk (one barrier per chunk)
#define NCH (Bn / BCH)   // 4 chunks

__device__ __forceinline__ int iclamp(int v, int lo, int hi) {
  return v < lo ? lo : (v > hi ? hi : v);
}
__device__ __forceinline__ f16x2 pkrtz(float lo, float hi) {
  return __builtin_amdgcn_cvt_pkrtz(lo, hi);
}
__device__ __forceinline__ float pkbits(float lo, float hi) {
  return __builtin_bit_cast(float, __builtin_amdgcn_cvt_pkrtz(lo, hi));
}
__device__ __forceinline__ f16x2 asf16x2(float w) {
  return __builtin_bit_cast(f16x2, w);
}
// (h01.hi, h23.lo) = middle overlapping pair
__device__ __forceinline__ f16x2 midpair(f16x2 h23, f16x2 h01) {
  unsigned r = __builtin_amdgcn_perm(__builtin_bit_cast(unsigned, h23),
                                     __builtin_bit_cast(unsigned, h01),
                                     0x05040302u);
  return __builtin_bit_cast(f16x2, r);
}

// Pack W TRANSPOSED (wpkT[t*27+o] = W[o][t], duplicated-half f16x2) + bias.
// Transposition makes K-gen's per-tap reads CONTIGUOUS 27-word runs ->
// s_load_dwordx16-batchable instead of stride-27 scalar gathers.
extern "C" __global__ void packW(const float* __restrict__ Wf,
                                 const float* __restrict__ bfp,
                                 float* __restrict__ wpk) {
  int i = threadIdx.x;
  if (i < 729) {
    int o = i / 27, t = i - o * 27;
    float v = Wf[i];
    wpk[t * 27 + o] = pkbits(v, v);
  } else if (i < 756) {
    float b = bfp[i - 729];
    wpk[i] = pkbits(b, b);
  }
}

extern "C" __global__ void __launch_bounds__(NT, 4)
fused3d(const float* __restrict__ img, const float* __restrict__ x,
        const float* __restrict__ wpk, float* __restrict__ out)
{
  __shared__ float sImgP[TILE_W];           // 3 KiB packed f16x2
  __shared__ float sXP[2][BCH][TILE_W];     // 24 KiB double-buffered

  const int tid = threadIdx.x;
  const int tx = tid & 7;          // w-pair 0..7
  const int ty = (tid >> 3) & 7;   // h 0..7
  const int tz = tid >> 6;         // d 0..3 (wave id)

  // T1 XCD swizzle: contiguous slab of 512 spatial tiles per XCD
  const int bid = blockIdx.x;
  const int s  = (bid & 7) * 512 + (bid >> 3);
  const int bx = s & 7, by = (s >> 3) & 15, bz = s >> 7;
  const int w0 = bx * TXv, h0 = by * TYt, d0 = bz * TZ;

  // ---- staging map: LDS word p = k*NT+tid holds x-halves (2p, 2p+1), clamped
  int off0[NPAIR], off1[NPAIR];
  float oki0[NPAIR], oki1[NPAIR];   // img zero-pad masks (conv SAME)
#pragma unroll
  for (int k = 0; k < NPAIR; ++k) {
    int p  = k * NT + tid;          // 0..767
    int r  = p / WPR;               // 0..63 (rows >=60 pad, never read)
    int c  = 2 * (p - r * WPR);     // 0..22 (halves >=18 pad, never read)
    int zz = r / HY;
    int yy = r - zz * HY;
    int gd = d0 + zz - 1, gh = h0 + yy - 1;
    int g0 = w0 + c - 1,  g1 = w0 + c;
    int base = (iclamp(gd, 0, Dm - 1) * Dm + iclamp(gh, 0, Dm - 1)) * Dm;
    off0[k] = base + iclamp(g0, 0, Dm - 1);
    off1[k] = base + iclamp(g1, 0, Dm - 1);
    bool rk = ((unsigned)gd < Dm) & ((unsigned)gh < Dm);
    oki0[k] = (rk & ((unsigned)g0 < Dm)) ? 1.f : 0.f;
    oki1[k] = (rk & ((unsigned)g1 < Dm)) ? 1.f : 0.f;
  }

  // ---- prologue: img (zero-masked) + x chunk 0 (4 batches) -> LDS buf0
  {
    float ri0[NPAIR], ri1[NPAIR];
#pragma unroll
    for (int k = 0; k < NPAIR; ++k) {
      ri0[k] = img[off0[k]] * oki0[k];
      ri1[k] = img[off1[k]] * oki1[k];
    }
    float rx0[BCH][NPAIR], rx1[BCH][NPAIR];
#pragma unroll
    for (int j = 0; j < BCH; ++j)
#pragma unroll
      for (int k = 0; k < NPAIR; ++k) {
        rx0[j][k] = x[(size_t)j * VOX + off0[k]];
        rx1[j][k] = x[(size_t)j * VOX + off1[k]];
      }
#pragma unroll
    for (int k = 0; k < NPAIR; ++k)
      sImgP[k * NT + tid] = pkbits(ri0[k], ri1[k]);
#pragma unroll
    for (int j = 0; j < BCH; ++j)
#pragma unroll
      for (int k = 0; k < NPAIR; ++k)
        sXP[0][j][k * NT + tid] = pkbits(rx0[j][k], rx1[j][k]);
  }
  __syncthreads();

  // ---- issue chunk 1 loads now: K-gen (~800 instr) covers their latency
  float nx0[BCH][NPAIR], nx1[BCH][NPAIR];
#pragma unroll
  for (int j = 0; j < BCH; ++j)
#pragma unroll
    for (int k = 0; k < NPAIR; ++k) {
      nx0[j][k] = x[(size_t)(BCH + j) * VOX + off0[k]];
      nx1[j][k] = x[(size_t)(BCH + j) * VOX + off1[k]];
    }

  // ---- K-gen: single pass over image window; W rows contiguous via wpkT
  const int tbase = (tz * HY + ty) * WPR + tx;
  f16x2 K2[27];
#pragma unroll
  for (int o = 0; o < 27; ++o) K2[o] = asf16x2(wpk[729 + o]);
#pragma unroll
  for (int rr = 0; rr < 9; ++rr) {
    const int wofs = tbase + ((rr / 3) * HY + (rr % 3)) * WPR;
    float u0 = sImgP[wofs], u1 = sImgP[wofs + 1];
    f16x2 h01 = asf16x2(u0), h23 = asf16x2(u1), h12 = midpair(h23, h01);
    const float* wA = wpk + (rr * 3 + 0) * 27;   // 27 contiguous words
    const float* wB = wpk + (rr * 3 + 1) * 27;
    const float* wC = wpk + (rr * 3 + 2) * 27;
#pragma unroll
    for (int o = 0; o < 27; ++o) {
      K2[o] = __builtin_elementwise_fma(asf16x2(wA[o]), h01, K2[o]);
      K2[o] = __builtin_elementwise_fma(asf16x2(wB[o]), h12, K2[o]);
      K2[o] = __builtin_elementwise_fma(asf16x2(wC[o]), h23, K2[o]);
    }
  }

  // ---- boundary tap masks (x zero-pad semantics; covers bias too)
  const int od = d0 + tz, oh = h0 + ty, ow = w0 + 2 * tx;
#pragma unroll
  for (int o = 0; o < 27; ++o) {
    const int di = o / 9, dj = (o / 3) % 3, dk = o % 3;
    const bool mm = ((unsigned)(od + di - 1) < Dm) & ((unsigned)(oh + dj - 1) < Dm);
    const float m0 = (mm & ((unsigned)(ow + dk - 1) < Dm)) ? 1.f : 0.f;
    const float m1 = (mm & ((unsigned)(ow + dk)     < Dm)) ? 1.f : 0.f;
    K2[o] *= pkrtz(m0, m1);
  }

  const size_t obase = (((size_t)od) * Dm + oh) * Dm + ow;

  // ---- main loop: 4 chunks x 4 batches, dbuf, ONE barrier per chunk.
  // Per iter: compute(buf cur) [~2000cy, covers loads issued last iter] ->
  // ds_write prefetched -> barrier -> issue loads for chunk+2.
  for (int ch = 0; ch < NCH; ++ch) {
    const int cur = ch & 1;

#pragma unroll
    for (int j = 0; j < BCH; ++j) {
      const float* sx = sXP[cur][j];
      f16x2 aA = {(__fp16)0.f, (__fp16)0.f};
      f16x2 aB = {(__fp16)0.f, (__fp16)0.f};
#pragma unroll
      for (int rr = 0; rr < 9; ++rr) {
        const int wofs = tbase + ((rr / 3) * HY + (rr % 3)) * WPR;
        float u0 = sx[wofs], u1 = sx[wofs + 1];
        f16x2 h01 = asf16x2(u0), h23 = asf16x2(u1), h12 = midpair(h23, h01);
        if (rr & 1) {
          aB = __builtin_elementwise_fma(K2[rr * 3 + 0], h01, aB);
          aB = __builtin_elementwise_fma(K2[rr * 3 + 1], h12, aB);
          aB = __builtin_elementwise_fma(K2[rr * 3 + 2], h23, aB);
        } else {
          aA = __builtin_elementwise_fma(K2[rr * 3 + 0], h01, aA);
          aA = __builtin_elementwise_fma(K2[rr * 3 + 1], h12, aA);
          aA = __builtin_elementwise_fma(K2[rr * 3 + 2], h23, aA);
        }
      }
      f16x2 acc = aA + aB;
      float2 st; st.x = (float)acc.x; st.y = (float)acc.y;
      *(float2*)&out[(size_t)(ch * BCH + j) * VOX + obase] = st;
    }

    if (ch + 1 < NCH) {              // write prefetched chunk into other buffer
#pragma unroll
      for (int j = 0; j < BCH; ++j)
#pragma unroll
        for (int k = 0; k < NPAIR; ++k)
          sXP[cur ^ 1][j][k * NT + tid] = pkbits(nx0[j][k], nx1[j][k]);
    }

    __syncthreads();                 // single barrier per chunk

    if (ch + 2 < NCH) {              // issue loads for chunk+2; next compute covers
      const float* xc = x + (size_t)(ch + 2) * BCH * VOX;
#pragma unroll
      for (int j = 0; j < BCH; ++j)
#pragma unroll
        for (int k = 0; k < NPAIR; ++k) {
          nx0[j][k] = xc[(size_t)j * VOX + off0[k]];
          nx1[j][k] = xc[(size_t)j * VOX + off1[k]];
        }
    }
  }
}

extern "C" void kernel_launch(void* const* d_in, const int* in_sizes, int n_in,
                              void* d_out, int out_size, void* d_ws, size_t ws_size,
                              hipStream_t stream) {
  const float* img = (const float*)d_in[0];
  const float* x   = (const float*)d_in[1];
  const float* Wf  = (const float*)d_in[2];
  const float* bf  = (const float*)d_in[3];
  float* out = (float*)d_out;
  float* wpk = (float*)d_ws;   // 756 floats (3 KiB): wpkT + bias, packed f16x2
  hipLaunchKernelGGL(packW, dim3(1), dim3(768), 0, stream, Wf, bf, wpk);
  hipLaunchKernelGGL(fused3d, dim3(4096), dim3(256), 0, stream, img, x, wpk, out);
}